// Round 1
// baseline (1824.654 us; speedup 1.0000x reference)
//
#include <hip/hip_runtime.h>

#define RR 3
#define NN 50000
#define EE 800000
#define FF 128
#define DD 128
#define AA 64
#define EPSF 1e-5f

__device__ __forceinline__ float wave_sum_f(float v) {
    v += __shfl_xor(v, 1);
    v += __shfl_xor(v, 2);
    v += __shfl_xor(v, 4);
    v += __shfl_xor(v, 8);
    v += __shfl_xor(v, 16);
    v += __shfl_xor(v, 32);
    return v;  // same value on all 64 lanes
}

// ---------------- aggregation: one wave per edge, atomic scatter ----------------
__global__ void agg_kernel(const float* __restrict__ feat,
                           const int* __restrict__ src,
                           const int* __restrict__ dst,
                           float* __restrict__ ssum,   // [R][N][F], pre-zeroed
                           float* __restrict__ deg) {  // [R][N], pre-zeroed
    int gid = blockIdx.x * blockDim.x + threadIdx.x;
    int wave = gid >> 6;
    int lane = gid & 63;
    int nwaves = (gridDim.x * blockDim.x) >> 6;
    const int total = RR * EE;
    for (int e = wave; e < total; e += nwaves) {
        int r = (e >= 2 * EE) ? 2 : ((e >= EE) ? 1 : 0);
        int ei = e - r * EE;
        int s = src[(size_t)r * EE + ei];
        int d = dst[(size_t)r * EE + ei];
        const float* fs = feat + (size_t)s * FF;
        float* o = ssum + ((size_t)r * NN + d) * FF;
        atomicAdd(o + lane, fs[lane]);
        atomicAdd(o + lane + 64, fs[lane + 64]);
        if (lane == 0) atomicAdd(deg + (size_t)r * NN + d, 1.0f);
    }
}

// ---------------- per-relation MLP: wave per node, weights in LDS ----------------
#define TB 512
#define WPB 8

__global__ __launch_bounds__(TB)
void transform_kernel(const float* __restrict__ feat,
                      float* shbuf,                      // ssum in, hfin out (in-place, NOT restrict)
                      const float* __restrict__ deg,
                      const float* __restrict__ W0, const float* __restrict__ b0,
                      const float* __restrict__ W1, const float* __restrict__ b1,
                      const float* __restrict__ ln_g, const float* __restrict__ ln_b,
                      const float* __restrict__ LN_g, const float* __restrict__ LN_b) {
    __shared__ float W0s[FF * DD];     // 64 KiB
    __shared__ float W1s[DD * DD];     // 64 KiB
    __shared__ float bias0[DD], bias1[DD], lg[DD], lb[DD], Lg[DD], Lb[DD];
    __shared__ float hbuf[WPB][FF];

    const int r = blockIdx.y;
    const int tid = threadIdx.x;

    for (int i = tid; i < FF * DD; i += TB) W0s[i] = W0[(size_t)r * FF * DD + i];
    for (int i = tid; i < DD * DD; i += TB) W1s[i] = W1[(size_t)r * DD * DD + i];
    if (tid < DD) {
        bias0[tid] = b0[r * DD + tid];
        bias1[tid] = b1[r * DD + tid];
        lg[tid] = ln_g[r * DD + tid];
        lb[tid] = ln_b[r * DD + tid];
        Lg[tid] = LN_g[tid];
        Lb[tid] = LN_b[tid];
    }
    __syncthreads();

    const int wave = tid >> 6, lane = tid & 63;
    const int gwave = blockIdx.x * WPB + wave;
    const int nwaves = gridDim.x * WPB;
    float* hb = hbuf[wave];

    for (int n = gwave; n < NN; n += nwaves) {
        const float* fr = feat + (size_t)n * FF;
        float* sh = shbuf + ((size_t)r * NN + n) * FF;
        float dg = deg[(size_t)r * NN + n];
        float inv = 1.0f / fmaxf(dg, 1.0f);
        float h0 = fr[lane] + sh[lane] * inv;
        float h1 = fr[lane + 64] + sh[lane + 64] * inv;

        hb[lane] = h0;
        hb[lane + 64] = h1;

        // layer 1
        float x0 = bias0[lane], x1 = bias0[lane + 64];
        #pragma unroll 16
        for (int f = 0; f < FF; ++f) {
            float hf = hb[f];
            x0 = fmaf(hf, W0s[f * DD + lane], x0);
            x1 = fmaf(hf, W0s[f * DD + lane + 64], x1);
        }
        float s = wave_sum_f(x0 + x1);
        float sq = wave_sum_f(x0 * x0 + x1 * x1);
        float mean = s * 0.0078125f;
        float var = sq * 0.0078125f - mean * mean;
        float rstd = rsqrtf(var + EPSF);
        x0 = fmaxf((x0 - mean) * rstd * lg[lane] + lb[lane], 0.0f);
        x1 = fmaxf((x1 - mean) * rstd * lg[lane + 64] + lb[lane + 64], 0.0f);

        // layer 2
        hb[lane] = x0;
        hb[lane + 64] = x1;
        float y0 = bias1[lane], y1 = bias1[lane + 64];
        #pragma unroll 16
        for (int f = 0; f < DD; ++f) {
            float hf = hb[f];
            y0 = fmaf(hf, W1s[f * DD + lane], y0);
            y1 = fmaf(hf, W1s[f * DD + lane + 64], y1);
        }
        s = wave_sum_f(y0 + y1);
        sq = wave_sum_f(y0 * y0 + y1 * y1);
        mean = s * 0.0078125f;
        var = sq * 0.0078125f - mean * mean;
        rstd = rsqrtf(var + EPSF);
        y0 = fmaxf((y0 - mean) * rstd * lg[lane] + lb[lane], 0.0f);
        y1 = fmaxf((y1 - mean) * rstd * lg[lane + 64] + lb[lane + 64], 0.0f);

        // final LayerNorm (shared gamma/beta)
        s = wave_sum_f(y0 + y1);
        sq = wave_sum_f(y0 * y0 + y1 * y1);
        mean = s * 0.0078125f;
        var = sq * 0.0078125f - mean * mean;
        rstd = rsqrtf(var + EPSF);
        y0 = (y0 - mean) * rstd * Lg[lane] + Lb[lane];
        y1 = (y1 - mean) * rstd * Lg[lane + 64] + Lb[lane + 64];

        sh[lane] = y0;
        sh[lane + 64] = y1;
    }
}

// ---------------- semantic attention + combine: wave per node ----------------
__global__ __launch_bounds__(256)
void attn_kernel(const float* __restrict__ hfin,   // [R][N][D]
                 const float* __restrict__ Wa1,    // [R][D][A]
                 const float* __restrict__ Wa2,    // [R][A]
                 float* __restrict__ out) {        // [N][D]
    __shared__ float Wa1s[RR * DD * AA];           // 96 KiB
    __shared__ float Wa2s[RR * AA];
    __shared__ float hb[4][RR][DD];

    const int tid = threadIdx.x;
    for (int i = tid; i < RR * DD * AA; i += 256) Wa1s[i] = Wa1[i];
    if (tid < RR * AA) Wa2s[tid] = Wa2[tid];
    __syncthreads();

    const int wave = tid >> 6, lane = tid & 63;
    const int gw = blockIdx.x * 4 + wave;
    const int nw = gridDim.x * 4;

    for (int n = gw; n < NN; n += nw) {
        float h0[RR], h1[RR];
        #pragma unroll
        for (int r = 0; r < RR; ++r) {
            h0[r] = hfin[((size_t)r * NN + n) * DD + lane];
            h1[r] = hfin[((size_t)r * NN + n) * DD + lane + 64];
            hb[wave][r][lane] = h0[r];
            hb[wave][r][lane + 64] = h1[r];
        }
        float e[RR];
        #pragma unroll
        for (int r = 0; r < RR; ++r) {
            float acc = 0.0f;
            #pragma unroll 16
            for (int d = 0; d < DD; ++d)
                acc = fmaf(hb[wave][r][d], Wa1s[(r * DD + d) * AA + lane], acc);
            float t = tanhf(acc);
            e[r] = wave_sum_f(t * Wa2s[r * AA + lane]);
        }
        float m = fmaxf(e[0], fmaxf(e[1], e[2]));
        float w0 = expf(e[0] - m), w1 = expf(e[1] - m), w2 = expf(e[2] - m);
        float inv = 1.0f / (w0 + w1 + w2);
        out[(size_t)n * DD + lane] = (w0 * h0[0] + w1 * h0[1] + w2 * h0[2]) * inv;
        out[(size_t)n * DD + lane + 64] = (w0 * h1[0] + w1 * h1[1] + w2 * h1[2]) * inv;
    }
}

extern "C" void kernel_launch(void* const* d_in, const int* in_sizes, int n_in,
                              void* d_out, int out_size, void* d_ws, size_t ws_size,
                              hipStream_t stream) {
    const float* feat = (const float*)d_in[0];
    const int*   src  = (const int*)d_in[1];
    const int*   dst  = (const int*)d_in[2];
    const float* W0   = (const float*)d_in[3];
    const float* b0   = (const float*)d_in[4];
    const float* W1   = (const float*)d_in[5];
    const float* b1   = (const float*)d_in[6];
    const float* ln_g = (const float*)d_in[7];
    const float* ln_b = (const float*)d_in[8];
    const float* LN_g = (const float*)d_in[9];
    const float* LN_b = (const float*)d_in[10];
    const float* Wa1  = (const float*)d_in[11];
    const float* Wa2  = (const float*)d_in[12];
    float* out = (float*)d_out;

    float* ssum = (float*)d_ws;                       // R*N*F floats
    float* deg  = ssum + (size_t)RR * NN * FF;        // R*N floats

    hipMemsetAsync(d_ws, 0, ((size_t)RR * NN * FF + (size_t)RR * NN) * sizeof(float), stream);
    agg_kernel<<<2048, 256, 0, stream>>>(feat, src, dst, ssum, deg);
    transform_kernel<<<dim3(85, RR), TB, 0, stream>>>(feat, ssum, deg, W0, b0, W1, b1,
                                                      ln_g, ln_b, LN_g, LN_b);
    attn_kernel<<<256, 256, 0, stream>>>(ssum, Wa1, Wa2, out);
}

// Round 2
// 1366.233 us; speedup vs baseline: 1.3355x; 1.3355x over previous
//
#include <hip/hip_runtime.h>

#define RR 3
#define NN 50000
#define EE 800000
#define FF 128
#define DD 128
#define AA 64
#define EPSF 1e-5f
#define RN (RR * NN)
#define RE (RR * EE)

__device__ __forceinline__ float wave_sum_f(float v) {
    v += __shfl_xor(v, 1);
    v += __shfl_xor(v, 2);
    v += __shfl_xor(v, 4);
    v += __shfl_xor(v, 8);
    v += __shfl_xor(v, 16);
    v += __shfl_xor(v, 32);
    return v;  // same value on all 64 lanes
}

// ---------------- CSR build: count, scan, scatter ----------------
__global__ void count_kernel(const int* __restrict__ dst, int* __restrict__ cnt) {
    int gid = blockIdx.x * blockDim.x + threadIdx.x;
    if (gid >= RE) return;
    int r = gid / EE;
    atomicAdd(&cnt[r * NN + dst[gid]], 1);
}

__global__ __launch_bounds__(1024)
void scan_kernel(const int* __restrict__ cnt, int* __restrict__ off) {
    __shared__ int part[1024];
    const int t = threadIdx.x;
    const int CH = (RN + 1023) / 1024;  // 147
    const int base = t * CH;
    int s = 0;
    for (int i = 0; i < CH; ++i) {
        int idx = base + i;
        if (idx < RN) s += cnt[idx];
    }
    part[t] = s;
    __syncthreads();
    // Hillis-Steele inclusive scan over 1024 partials
    for (int d = 1; d < 1024; d <<= 1) {
        int v = (t >= d) ? part[t - d] : 0;
        __syncthreads();
        part[t] += v;
        __syncthreads();
    }
    int run = (t == 0) ? 0 : part[t - 1];
    for (int i = 0; i < CH; ++i) {
        int idx = base + i;
        if (idx < RN) { off[idx] = run; run += cnt[idx]; }
    }
}

__global__ void scatter_kernel(const int* __restrict__ src, const int* __restrict__ dst,
                               int* __restrict__ off, int* __restrict__ csr) {
    int gid = blockIdx.x * blockDim.x + threadIdx.x;
    if (gid >= RE) return;
    int r = gid / EE;
    int pos = atomicAdd(&off[r * NN + dst[gid]], 1);  // off becomes end-offset
    csr[pos] = src[gid];
}

// ---------------- aggregation: wave per (r,node), register gather ----------------
__global__ __launch_bounds__(256)
void gather_kernel(const float* __restrict__ feat,
                   const int* __restrict__ csr,
                   const int* __restrict__ off,   // end offsets (post-scatter)
                   const int* __restrict__ cnt,
                   float* __restrict__ ssum) {    // [R][N][F] <- neighbor MEAN
    int gid = blockIdx.x * blockDim.x + threadIdx.x;
    int w = gid >> 6, lane = gid & 63;
    if (w >= RN) return;
    int c = cnt[w];
    int end = off[w];
    int start = end - c;
    const float2* f2 = (const float2*)feat;
    float ax = 0.0f, ay = 0.0f;
    for (int j = start; j < end; ++j) {
        int s = csr[j];
        float2 v = f2[(size_t)s * 64 + lane];
        ax += v.x;
        ay += v.y;
    }
    float inv = 1.0f / fmaxf((float)c, 1.0f);
    float2 o; o.x = ax * inv; o.y = ay * inv;
    ((float2*)ssum)[(size_t)w * 64 + lane] = o;
}

// ---------------- per-relation MLP: 4 nodes per wave, weights in LDS ----------------
#define TB 512
#define WPB 8
#define NPW 4

__global__ __launch_bounds__(TB)
void transform_kernel(const float* __restrict__ feat,
                      float* shbuf,                      // ssum(mean) in, hfin out (in-place)
                      const float* __restrict__ W0, const float* __restrict__ b0,
                      const float* __restrict__ W1, const float* __restrict__ b1,
                      const float* __restrict__ ln_g, const float* __restrict__ ln_b,
                      const float* __restrict__ LN_g, const float* __restrict__ LN_b) {
    __shared__ float W0s[FF * DD];                 // 64 KiB
    __shared__ float W1s[DD * DD];                 // 64 KiB
    __shared__ float bias0[DD], bias1[DD], lg[DD], lb[DD], Lg[DD], Lb[DD];
    __shared__ float hbuf[WPB][NPW][FF];           // 16 KiB

    const int r = blockIdx.y;
    const int tid = threadIdx.x;

    for (int i = tid; i < FF * DD; i += TB) W0s[i] = W0[(size_t)r * FF * DD + i];
    for (int i = tid; i < DD * DD; i += TB) W1s[i] = W1[(size_t)r * DD * DD + i];
    if (tid < DD) {
        bias0[tid] = b0[r * DD + tid];
        bias1[tid] = b1[r * DD + tid];
        lg[tid] = ln_g[r * DD + tid];
        lb[tid] = ln_b[r * DD + tid];
        Lg[tid] = LN_g[tid];
        Lb[tid] = LN_b[tid];
    }
    __syncthreads();

    const int wave = tid >> 6, lane = tid & 63;
    float (*hb)[FF] = hbuf[wave];
    const int g0 = blockIdx.x * WPB + wave;
    const int ng = gridDim.x * WPB;
    const float g_lo = lg[lane], g_hi = lg[lane + 64];
    const float be_lo = lb[lane], be_hi = lb[lane + 64];

    for (int g = g0; g < NN / NPW; g += ng) {
        const int n0 = g * NPW;
        float x0[NPW], x1[NPW];

        #pragma unroll
        for (int k = 0; k < NPW; ++k) {
            const float2* fr = (const float2*)(feat + (size_t)(n0 + k) * FF);
            const float2* sh = (const float2*)(shbuf + ((size_t)r * NN + n0 + k) * FF);
            float2 a = fr[lane], b = sh[lane];
            hb[k][2 * lane] = a.x + b.x;
            hb[k][2 * lane + 1] = a.y + b.y;
        }

        // layer 1
        #pragma unroll
        for (int k = 0; k < NPW; ++k) { x0[k] = bias0[lane]; x1[k] = bias0[lane + 64]; }
        #pragma unroll 8
        for (int f = 0; f < FF; ++f) {
            float w0 = W0s[f * DD + lane];
            float w1 = W0s[f * DD + lane + 64];
            #pragma unroll
            for (int k = 0; k < NPW; ++k) {
                float hf = hb[k][f];
                x0[k] = fmaf(hf, w0, x0[k]);
                x1[k] = fmaf(hf, w1, x1[k]);
            }
        }
        #pragma unroll
        for (int k = 0; k < NPW; ++k) {
            float s = wave_sum_f(x0[k] + x1[k]);
            float sq = wave_sum_f(x0[k] * x0[k] + x1[k] * x1[k]);
            float mean = s * 0.0078125f;
            float var = sq * 0.0078125f - mean * mean;
            float rstd = rsqrtf(var + EPSF);
            x0[k] = fmaxf((x0[k] - mean) * rstd * g_lo + be_lo, 0.0f);
            x1[k] = fmaxf((x1[k] - mean) * rstd * g_hi + be_hi, 0.0f);
            hb[k][lane] = x0[k];
            hb[k][lane + 64] = x1[k];
        }

        // layer 2
        #pragma unroll
        for (int k = 0; k < NPW; ++k) { x0[k] = bias1[lane]; x1[k] = bias1[lane + 64]; }
        #pragma unroll 8
        for (int f = 0; f < DD; ++f) {
            float w0 = W1s[f * DD + lane];
            float w1 = W1s[f * DD + lane + 64];
            #pragma unroll
            for (int k = 0; k < NPW; ++k) {
                float hf = hb[k][f];
                x0[k] = fmaf(hf, w0, x0[k]);
                x1[k] = fmaf(hf, w1, x1[k]);
            }
        }
        #pragma unroll
        for (int k = 0; k < NPW; ++k) {
            float s = wave_sum_f(x0[k] + x1[k]);
            float sq = wave_sum_f(x0[k] * x0[k] + x1[k] * x1[k]);
            float mean = s * 0.0078125f;
            float var = sq * 0.0078125f - mean * mean;
            float rstd = rsqrtf(var + EPSF);
            float y0 = fmaxf((x0[k] - mean) * rstd * g_lo + be_lo, 0.0f);
            float y1 = fmaxf((x1[k] - mean) * rstd * g_hi + be_hi, 0.0f);

            // final LayerNorm (shared gamma/beta)
            s = wave_sum_f(y0 + y1);
            sq = wave_sum_f(y0 * y0 + y1 * y1);
            mean = s * 0.0078125f;
            var = sq * 0.0078125f - mean * mean;
            rstd = rsqrtf(var + EPSF);
            y0 = (y0 - mean) * rstd * Lg[lane] + Lb[lane];
            y1 = (y1 - mean) * rstd * Lg[lane + 64] + Lb[lane + 64];

            float* sh = shbuf + ((size_t)r * NN + n0 + k) * FF;
            sh[lane] = y0;
            sh[lane + 64] = y1;
        }
    }
}

// ---------------- semantic attention + combine: wave per node ----------------
__global__ __launch_bounds__(256)
void attn_kernel(const float* __restrict__ hfin,   // [R][N][D]
                 const float* __restrict__ Wa1,    // [R][D][A]
                 const float* __restrict__ Wa2,    // [R][A]
                 float* __restrict__ out) {        // [N][D]
    __shared__ float Wa1s[RR * DD * AA];           // 96 KiB
    __shared__ float Wa2s[RR * AA];
    __shared__ float hb[4][RR][DD];

    const int tid = threadIdx.x;
    for (int i = tid; i < RR * DD * AA; i += 256) Wa1s[i] = Wa1[i];
    if (tid < RR * AA) Wa2s[tid] = Wa2[tid];
    __syncthreads();

    const int wave = tid >> 6, lane = tid & 63;
    const int gw = blockIdx.x * 4 + wave;
    const int nw = gridDim.x * 4;

    for (int n = gw; n < NN; n += nw) {
        float h0[RR], h1[RR];
        #pragma unroll
        for (int r = 0; r < RR; ++r) {
            h0[r] = hfin[((size_t)r * NN + n) * DD + lane];
            h1[r] = hfin[((size_t)r * NN + n) * DD + lane + 64];
            hb[wave][r][lane] = h0[r];
            hb[wave][r][lane + 64] = h1[r];
        }
        float e[RR];
        #pragma unroll
        for (int r = 0; r < RR; ++r) {
            float acc = 0.0f;
            #pragma unroll 16
            for (int d = 0; d < DD; ++d)
                acc = fmaf(hb[wave][r][d], Wa1s[(r * DD + d) * AA + lane], acc);
            float t = tanhf(acc);
            e[r] = wave_sum_f(t * Wa2s[r * AA + lane]);
        }
        float m = fmaxf(e[0], fmaxf(e[1], e[2]));
        float w0 = expf(e[0] - m), w1 = expf(e[1] - m), w2 = expf(e[2] - m);
        float inv = 1.0f / (w0 + w1 + w2);
        out[(size_t)n * DD + lane] = (w0 * h0[0] + w1 * h0[1] + w2 * h0[2]) * inv;
        out[(size_t)n * DD + lane + 64] = (w0 * h1[0] + w1 * h1[1] + w2 * h1[2]) * inv;
    }
}

extern "C" void kernel_launch(void* const* d_in, const int* in_sizes, int n_in,
                              void* d_out, int out_size, void* d_ws, size_t ws_size,
                              hipStream_t stream) {
    const float* feat = (const float*)d_in[0];
    const int*   src  = (const int*)d_in[1];
    const int*   dst  = (const int*)d_in[2];
    const float* W0   = (const float*)d_in[3];
    const float* b0   = (const float*)d_in[4];
    const float* W1   = (const float*)d_in[5];
    const float* b1   = (const float*)d_in[6];
    const float* ln_g = (const float*)d_in[7];
    const float* ln_b = (const float*)d_in[8];
    const float* LN_g = (const float*)d_in[9];
    const float* LN_b = (const float*)d_in[10];
    const float* Wa1  = (const float*)d_in[11];
    const float* Wa2  = (const float*)d_in[12];
    float* out = (float*)d_out;

    // workspace layout: ssum first (proven-resident region), CSR arrays after
    float* ssum = (float*)d_ws;                    // RN*FF floats (76.8 MB)
    int*   cnt  = (int*)(ssum + (size_t)RN * FF);  // RN ints
    int*   off  = cnt + RN;                        // RN ints
    int*   csr  = off + RN;                        // RE ints

    hipMemsetAsync(cnt, 0, (size_t)RN * sizeof(int), stream);
    count_kernel<<<(RE + 255) / 256, 256, 0, stream>>>(dst, cnt);
    scan_kernel<<<1, 1024, 0, stream>>>(cnt, off);
    scatter_kernel<<<(RE + 255) / 256, 256, 0, stream>>>(src, dst, off, csr);
    gather_kernel<<<(RN * 64 + 255) / 256, 256, 0, stream>>>(feat, csr, off, cnt, ssum);
    transform_kernel<<<dim3((NN / NPW + WPB - 1) / WPB, RR), TB, 0, stream>>>(
        feat, ssum, W0, b0, W1, b1, ln_g, ln_b, LN_g, LN_b);
    attn_kernel<<<256, 256, 0, stream>>>(ssum, Wa1, Wa2, out);
}

// Round 3
// 651.737 us; speedup vs baseline: 2.7997x; 2.0963x over previous
//
#include <hip/hip_runtime.h>

#define RR 3
#define NN 50000
#define EE 800000
#define FF 128
#define DD 128
#define AA 64
#define EPSF 1e-5f
#define RN (RR * NN)
#define RE (RR * EE)

typedef __attribute__((ext_vector_type(8))) short bf16x8;
typedef __attribute__((ext_vector_type(4))) float f32x4;

__device__ __forceinline__ short f2bs(float x) {
    union { float f; unsigned u; } v; v.f = x;
    unsigned rr = (v.u + 0x7fffu + ((v.u >> 16) & 1u)) >> 16;  // RNE
    return (short)(rr & 0xffffu);
}

// ---------------- CSR build: count, 3-phase scan, scatter ----------------
__global__ void count_kernel(const int* __restrict__ dst, int* __restrict__ cnt) {
    int gid = blockIdx.x * blockDim.x + threadIdx.x;
    if (gid >= RE) return;
    int r = gid / EE;
    atomicAdd(&cnt[r * NN + dst[gid]], 1);
}

__global__ __launch_bounds__(256)
void scan_phase1(const int* __restrict__ cnt, int* __restrict__ bsum) {
    __shared__ int sm[4];
    int b = blockIdx.x, t = threadIdx.x;
    int base = b * 1024 + t * 4;
    int s = 0;
    if (base + 3 < RN) {
        int4 v = *(const int4*)(cnt + base);
        s = v.x + v.y + v.z + v.w;
    } else {
        for (int i = 0; i < 4; ++i) if (base + i < RN) s += cnt[base + i];
    }
    #pragma unroll
    for (int m = 1; m < 64; m <<= 1) s += __shfl_xor(s, m);
    if ((t & 63) == 0) sm[t >> 6] = s;
    __syncthreads();
    if (t == 0) bsum[b] = sm[0] + sm[1] + sm[2] + sm[3];
}

__global__ __launch_bounds__(256)
void scan_phase2(int* __restrict__ bsum, int nb) {   // single block
    __shared__ int sm[256];
    int t = threadIdx.x;
    int v = (t < nb) ? bsum[t] : 0;
    sm[t] = v;
    __syncthreads();
    for (int d = 1; d < 256; d <<= 1) {
        int u = (t >= d) ? sm[t - d] : 0;
        __syncthreads();
        sm[t] += u;
        __syncthreads();
    }
    if (t < nb) bsum[t] = sm[t] - v;   // exclusive
}

__global__ __launch_bounds__(256)
void scan_phase3(const int* __restrict__ cnt, const int* __restrict__ bsum,
                 int* __restrict__ off) {
    __shared__ int sm[256];
    int b = blockIdx.x, t = threadIdx.x;
    int base = b * 1024 + t * 4;
    int c0 = 0, c1 = 0, c2 = 0, c3 = 0;
    if (base + 3 < RN) {
        int4 v = *(const int4*)(cnt + base);
        c0 = v.x; c1 = v.y; c2 = v.z; c3 = v.w;
    } else {
        if (base + 0 < RN) c0 = cnt[base + 0];
        if (base + 1 < RN) c1 = cnt[base + 1];
        if (base + 2 < RN) c2 = cnt[base + 2];
        if (base + 3 < RN) c3 = cnt[base + 3];
    }
    int s = c0 + c1 + c2 + c3;
    sm[t] = s;
    __syncthreads();
    for (int d = 1; d < 256; d <<= 1) {
        int u = (t >= d) ? sm[t - d] : 0;
        __syncthreads();
        sm[t] += u;
        __syncthreads();
    }
    int pre = bsum[b] + sm[t] - s;   // exclusive within chunk + chunk base
    if (base + 0 < RN) off[base + 0] = pre;
    if (base + 1 < RN) off[base + 1] = pre + c0;
    if (base + 2 < RN) off[base + 2] = pre + c0 + c1;
    if (base + 3 < RN) off[base + 3] = pre + c0 + c1 + c2;
}

__global__ void scatter_kernel(const int* __restrict__ src, const int* __restrict__ dst,
                               int* __restrict__ off, int* __restrict__ csr) {
    int gid = blockIdx.x * blockDim.x + threadIdx.x;
    if (gid >= RE) return;
    int r = gid / EE;
    int pos = atomicAdd(&off[r * NN + dst[gid]], 1);  // off becomes end-offset
    csr[pos] = src[gid];
}

// ---------------- aggregation: wave per (r,node), register gather ----------------
__global__ __launch_bounds__(256)
void gather_kernel(const float* __restrict__ feat,
                   const int* __restrict__ csr,
                   const int* __restrict__ off,   // end offsets (post-scatter)
                   const int* __restrict__ cnt,
                   float* __restrict__ ssum) {    // [R][N][F] <- neighbor MEAN
    int gid = blockIdx.x * blockDim.x + threadIdx.x;
    int w = gid >> 6, lane = gid & 63;
    if (w >= RN) return;
    int c = cnt[w];
    int end = off[w];
    int start = end - c;
    const float2* f2 = (const float2*)feat;
    float ax = 0.0f, ay = 0.0f;
    for (int j = start; j < end; ++j) {
        int s = csr[j];
        float2 v = f2[(size_t)s * 64 + lane];
        ax += v.x;
        ay += v.y;
    }
    float inv = 1.0f / fmaxf((float)c, 1.0f);
    float2 o; o.x = ax * inv; o.y = ay * inv;
    ((float2*)ssum)[(size_t)w * 64 + lane] = o;
}

// ---------------- fused MFMA transform (2x Linear+LN+relu, final LN, attn scores) ----
#define TW 8

__device__ __forceinline__ void mfma_layer(const bf16x8 A[2][4], const short* Wlds,
                                           int g8, int c, f32x4 acc[2][8]) {
    #pragma unroll
    for (int kk = 0; kk < 4; ++kk) {
        #pragma unroll
        for (int t = 0; t < 8; ++t) {
            int d = t * 16 + c;
            bf16x8 B = *(const bf16x8*)&Wlds[d * 128 + ((kk * 32 + g8) ^ ((d & 7) << 3))];
            acc[0][t] = __builtin_amdgcn_mfma_f32_16x16x32_bf16(A[0][kk], B, acc[0][t], 0, 0, 0);
            acc[1][t] = __builtin_amdgcn_mfma_f32_16x16x32_bf16(A[1][kk], B, acc[1][t], 0, 0, 0);
        }
    }
}

template <bool RELU, bool BIAS>
__device__ __forceinline__ void ln_block(f32x4 acc[2][8], const float* bias,
                                         const float* gam, const float* bet, int c) {
    #pragma unroll
    for (int sub = 0; sub < 2; ++sub) {
        float s0 = 0, s1 = 0, s2 = 0, s3 = 0, p0 = 0, p1 = 0, p2 = 0, p3 = 0;
        #pragma unroll
        for (int t = 0; t < 8; ++t) {
            if (BIAS) {
                float bb = bias[t * 16 + c];
                acc[sub][t][0] += bb; acc[sub][t][1] += bb;
                acc[sub][t][2] += bb; acc[sub][t][3] += bb;
            }
            s0 += acc[sub][t][0]; p0 += acc[sub][t][0] * acc[sub][t][0];
            s1 += acc[sub][t][1]; p1 += acc[sub][t][1] * acc[sub][t][1];
            s2 += acc[sub][t][2]; p2 += acc[sub][t][2] * acc[sub][t][2];
            s3 += acc[sub][t][3]; p3 += acc[sub][t][3] * acc[sub][t][3];
        }
        #pragma unroll
        for (int m = 1; m < 16; m <<= 1) {
            s0 += __shfl_xor(s0, m); s1 += __shfl_xor(s1, m);
            s2 += __shfl_xor(s2, m); s3 += __shfl_xor(s3, m);
            p0 += __shfl_xor(p0, m); p1 += __shfl_xor(p1, m);
            p2 += __shfl_xor(p2, m); p3 += __shfl_xor(p3, m);
        }
        const float inv = 1.0f / 128.0f;
        float mu0 = s0 * inv, mu1 = s1 * inv, mu2 = s2 * inv, mu3 = s3 * inv;
        float r0 = rsqrtf(p0 * inv - mu0 * mu0 + EPSF);
        float r1 = rsqrtf(p1 * inv - mu1 * mu1 + EPSF);
        float r2 = rsqrtf(p2 * inv - mu2 * mu2 + EPSF);
        float r3 = rsqrtf(p3 * inv - mu3 * mu3 + EPSF);
        #pragma unroll
        for (int t = 0; t < 8; ++t) {
            float gg = gam[t * 16 + c], bb = bet[t * 16 + c];
            float v0 = (acc[sub][t][0] - mu0) * r0 * gg + bb;
            float v1 = (acc[sub][t][1] - mu1) * r1 * gg + bb;
            float v2 = (acc[sub][t][2] - mu2) * r2 * gg + bb;
            float v3 = (acc[sub][t][3] - mu3) * r3 * gg + bb;
            if (RELU) {
                v0 = fmaxf(v0, 0.f); v1 = fmaxf(v1, 0.f);
                v2 = fmaxf(v2, 0.f); v3 = fmaxf(v3, 0.f);
            }
            acc[sub][t][0] = v0; acc[sub][t][1] = v1;
            acc[sub][t][2] = v2; acc[sub][t][3] = v3;
        }
    }
}

__device__ __forceinline__ void store_ht(const f32x4 acc[2][8], short* myht, int g, int c) {
    #pragma unroll
    for (int sub = 0; sub < 2; ++sub)
        #pragma unroll
        for (int t = 0; t < 8; ++t) {
            int col = t * 16 + c;
            #pragma unroll
            for (int qq = 0; qq < 4; ++qq) {
                int row = sub * 16 + g * 4 + qq;
                myht[row * 128 + (col ^ ((row & 7) << 3))] = f2bs(acc[sub][t][qq]);
            }
        }
}

__device__ __forceinline__ void load_A(bf16x8 A[2][4], const short* myht, int g8, int c) {
    #pragma unroll
    for (int sub = 0; sub < 2; ++sub)
        #pragma unroll
        for (int kk = 0; kk < 4; ++kk) {
            int row = sub * 16 + c;
            A[sub][kk] = *(const bf16x8*)&myht[row * 128 + ((kk * 32 + g8) ^ ((row & 7) << 3))];
        }
}

__global__ __launch_bounds__(512)
void fused_transform(const float* __restrict__ feat, float* hbuf,  // ssum in, hfin out
                     const float* __restrict__ W0, const float* __restrict__ b0,
                     const float* __restrict__ W1, const float* __restrict__ b1,
                     const float* __restrict__ ln_g, const float* __restrict__ ln_b,
                     const float* __restrict__ LN_g, const float* __restrict__ LN_b,
                     const float* __restrict__ Wa1, const float* __restrict__ Wa2,
                     float* __restrict__ evec) {
    __shared__ short W0t[FF * DD];        // 32 KiB, [d][k] bf16, XOR-swizzled
    __shared__ short W1t[DD * DD];        // 32 KiB
    __shared__ short Wa1t[AA * DD];       // 16 KiB, [a][k]
    __shared__ short ht[TW][32 * DD];     // 64 KiB per-wave h-tiles
    __shared__ float b0s[DD], b1s[DD], lgs[DD], lbs[DD], Lgs[DD], Lbs[DD], wa2s[AA];

    const int r = blockIdx.y;
    const int tid = threadIdx.x;

    for (int i = tid; i < FF * DD; i += 512) {
        int k = i >> 7, d = i & 127;                 // global read coalesced over d
        int idx = d * 128 + (k ^ ((d & 7) << 3));
        W0t[idx] = f2bs(W0[(size_t)r * FF * DD + i]);
        W1t[idx] = f2bs(W1[(size_t)r * DD * DD + i]);
    }
    for (int i = tid; i < DD * AA; i += 512) {
        int k = i >> 6, a = i & 63;
        Wa1t[a * 128 + (k ^ ((a & 7) << 3))] = f2bs(Wa1[(size_t)r * DD * AA + i]);
    }
    if (tid < DD) {
        b0s[tid] = b0[r * DD + tid];
        b1s[tid] = b1[r * DD + tid];
        lgs[tid] = ln_g[r * DD + tid];
        lbs[tid] = ln_b[r * DD + tid];
        Lgs[tid] = LN_g[tid];
        Lbs[tid] = LN_b[tid];
    }
    if (tid < AA) wa2s[tid] = Wa2[r * AA + tid];
    __syncthreads();   // only barrier; per-wave private work below

    const int wv = tid >> 6, ln = tid & 63;
    const int g = ln >> 4, c = ln & 15;
    const int g8 = g * 8;
    short* myht = ht[wv];

    const int ntiles = (NN + 31) / 32;
    for (int tile = blockIdx.x * TW + wv; tile < ntiles; tile += gridDim.x * TW) {
        const int nbase = tile * 32;

        // build layer-1 A fragments from feat + neighbor-mean (fp32 -> bf16)
        bf16x8 A1[2][4];
        #pragma unroll
        for (int sub = 0; sub < 2; ++sub) {
            int n = nbase + sub * 16 + c;
            if (n > NN - 1) n = NN - 1;              // duplicate row; stores guarded
            const float* fp = feat + (size_t)n * FF;
            const float* sp = hbuf + ((size_t)r * NN + n) * FF;
            #pragma unroll
            for (int kk = 0; kk < 4; ++kk) {
                int col0 = kk * 32 + g8;
                f32x4 a0 = *(const f32x4*)(fp + col0);
                f32x4 a1 = *(const f32x4*)(fp + col0 + 4);
                f32x4 s0 = *(const f32x4*)(sp + col0);
                f32x4 s1 = *(const f32x4*)(sp + col0 + 4);
                bf16x8 A;
                A[0] = f2bs(a0.x + s0.x); A[1] = f2bs(a0.y + s0.y);
                A[2] = f2bs(a0.z + s0.z); A[3] = f2bs(a0.w + s0.w);
                A[4] = f2bs(a1.x + s1.x); A[5] = f2bs(a1.y + s1.y);
                A[6] = f2bs(a1.z + s1.z); A[7] = f2bs(a1.w + s1.w);
                A1[sub][kk] = A;
            }
        }

        f32x4 acc[2][8];
        #pragma unroll
        for (int sub = 0; sub < 2; ++sub)
            #pragma unroll
            for (int t = 0; t < 8; ++t) acc[sub][t] = (f32x4){0.f, 0.f, 0.f, 0.f};

        // layer 1
        mfma_layer(A1, W0t, g8, c, acc);
        ln_block<true, true>(acc, b0s, lgs, lbs, c);
        store_ht(acc, myht, g, c);

        // layer 2
        bf16x8 A2[2][4];
        load_A(A2, myht, g8, c);
        #pragma unroll
        for (int sub = 0; sub < 2; ++sub)
            #pragma unroll
            for (int t = 0; t < 8; ++t) acc[sub][t] = (f32x4){0.f, 0.f, 0.f, 0.f};
        mfma_layer(A2, W1t, g8, c, acc);
        ln_block<true, true>(acc, b1s, lgs, lbs, c);
        // final LayerNorm (no relu, shared gamma/beta)
        ln_block<false, false>(acc, nullptr, Lgs, Lbs, c);
        store_ht(acc, myht, g, c);

        // store h to global (in-place over ssum; this tile's rows already consumed)
        #pragma unroll
        for (int sub = 0; sub < 2; ++sub)
            #pragma unroll
            for (int t = 0; t < 8; ++t)
                #pragma unroll
                for (int qq = 0; qq < 4; ++qq) {
                    int n = nbase + sub * 16 + g * 4 + qq;
                    if (n < NN) hbuf[((size_t)r * NN + n) * FF + t * 16 + c] = acc[sub][t][qq];
                }

        // semantic attention scores: e = tanh(h @ Wa1) . Wa2
        bf16x8 A3[2][4];
        load_A(A3, myht, g8, c);
        f32x4 accA[2][4];
        #pragma unroll
        for (int sub = 0; sub < 2; ++sub)
            #pragma unroll
            for (int t = 0; t < 4; ++t) accA[sub][t] = (f32x4){0.f, 0.f, 0.f, 0.f};
        #pragma unroll
        for (int kk = 0; kk < 4; ++kk)
            #pragma unroll
            for (int t = 0; t < 4; ++t) {
                int a_ = t * 16 + c;
                bf16x8 B = *(const bf16x8*)&Wa1t[a_ * 128 + ((kk * 32 + g8) ^ ((a_ & 7) << 3))];
                accA[0][t] = __builtin_amdgcn_mfma_f32_16x16x32_bf16(A3[0][kk], B, accA[0][t], 0, 0, 0);
                accA[1][t] = __builtin_amdgcn_mfma_f32_16x16x32_bf16(A3[1][kk], B, accA[1][t], 0, 0, 0);
            }
        #pragma unroll
        for (int sub = 0; sub < 2; ++sub) {
            float e0 = 0, e1 = 0, e2 = 0, e3 = 0;
            #pragma unroll
            for (int t = 0; t < 4; ++t) {
                float w2v = wa2s[t * 16 + c];
                e0 += tanhf(accA[sub][t][0]) * w2v;
                e1 += tanhf(accA[sub][t][1]) * w2v;
                e2 += tanhf(accA[sub][t][2]) * w2v;
                e3 += tanhf(accA[sub][t][3]) * w2v;
            }
            #pragma unroll
            for (int m = 1; m < 16; m <<= 1) {
                e0 += __shfl_xor(e0, m); e1 += __shfl_xor(e1, m);
                e2 += __shfl_xor(e2, m); e3 += __shfl_xor(e3, m);
            }
            int nb = nbase + sub * 16 + g * 4;
            if (c == 0 && nb + 0 < NN) evec[(size_t)r * NN + nb + 0] = e0;
            if (c == 1 && nb + 1 < NN) evec[(size_t)r * NN + nb + 1] = e1;
            if (c == 2 && nb + 2 < NN) evec[(size_t)r * NN + nb + 2] = e2;
            if (c == 3 && nb + 3 < NN) evec[(size_t)r * NN + nb + 3] = e3;
        }
    }
}

// ---------------- softmax over relations + weighted combine ----------------
__global__ __launch_bounds__(256)
void combine_kernel(const float* __restrict__ hfin,   // [R][N][D]
                    const float* __restrict__ evec,   // [R][N]
                    float* __restrict__ out) {        // [N][D]
    int gid = blockIdx.x * blockDim.x + threadIdx.x;
    if (gid >= NN * 64) return;
    int n = gid >> 6, j = gid & 63;
    float e0 = evec[n], e1 = evec[NN + n], e2 = evec[2 * NN + n];
    float m = fmaxf(e0, fmaxf(e1, e2));
    float w0 = __expf(e0 - m), w1 = __expf(e1 - m), w2 = __expf(e2 - m);
    float inv = 1.0f / (w0 + w1 + w2);
    w0 *= inv; w1 *= inv; w2 *= inv;
    const float2* h0 = (const float2*)(hfin + (size_t)n * DD);
    const float2* h1 = (const float2*)(hfin + ((size_t)NN + n) * DD);
    const float2* h2 = (const float2*)(hfin + ((size_t)2 * NN + n) * DD);
    float2 a = h0[j], b = h1[j], d = h2[j];
    float2 o;
    o.x = w0 * a.x + w1 * b.x + w2 * d.x;
    o.y = w0 * a.y + w1 * b.y + w2 * d.y;
    ((float2*)out)[(size_t)n * 64 + j] = o;
}

extern "C" void kernel_launch(void* const* d_in, const int* in_sizes, int n_in,
                              void* d_out, int out_size, void* d_ws, size_t ws_size,
                              hipStream_t stream) {
    const float* feat = (const float*)d_in[0];
    const int*   src  = (const int*)d_in[1];
    const int*   dst  = (const int*)d_in[2];
    const float* W0   = (const float*)d_in[3];
    const float* b0   = (const float*)d_in[4];
    const float* W1   = (const float*)d_in[5];
    const float* b1   = (const float*)d_in[6];
    const float* ln_g = (const float*)d_in[7];
    const float* ln_b = (const float*)d_in[8];
    const float* LN_g = (const float*)d_in[9];
    const float* LN_b = (const float*)d_in[10];
    const float* Wa1  = (const float*)d_in[11];
    const float* Wa2  = (const float*)d_in[12];
    float* out = (float*)d_out;

    float* ssum = (float*)d_ws;                    // RN*FF floats; becomes hfin in-place
    int*   cnt  = (int*)(ssum + (size_t)RN * FF);  // RN
    int*   off  = cnt + RN;                        // RN
    int*   csr  = off + RN;                        // RE
    float* evec = (float*)(csr + RE);              // RN
    int*   bsum = (int*)(evec + RN);               // 147

    const int NB = (RN + 1023) / 1024;             // 147

    hipMemsetAsync(cnt, 0, (size_t)RN * sizeof(int), stream);
    count_kernel<<<(RE + 255) / 256, 256, 0, stream>>>(dst, cnt);
    scan_phase1<<<NB, 256, 0, stream>>>(cnt, bsum);
    scan_phase2<<<1, 256, 0, stream>>>(bsum, NB);
    scan_phase3<<<NB, 256, 0, stream>>>(cnt, bsum, off);
    scatter_kernel<<<(RE + 255) / 256, 256, 0, stream>>>(src, dst, off, csr);
    gather_kernel<<<(RN * 64 + 255) / 256, 256, 0, stream>>>(feat, csr, off, cnt, ssum);

    const int ntiles = (NN + 31) / 32;             // 1563
    fused_transform<<<dim3((ntiles + TW - 1) / TW, RR), 512, 0, stream>>>(
        feat, ssum, W0, b0, W1, b1, ln_g, ln_b, LN_g, LN_b, Wa1, Wa2, evec);
    combine_kernel<<<(NN * 64 + 255) / 256, 256, 0, stream>>>(ssum, evec, out);
}

// Round 4
// 619.663 us; speedup vs baseline: 2.9446x; 1.0518x over previous
//
#include <hip/hip_runtime.h>

#define RR 3
#define NN 50000
#define EE 800000
#define FF 128
#define DD 128
#define AA 64
#define EPSF 1e-5f
#define RN (RR * NN)
#define RE (RR * EE)

typedef __attribute__((ext_vector_type(8))) short bf16x8;
typedef __attribute__((ext_vector_type(4))) float f32x4;
typedef __attribute__((ext_vector_type(4))) short s16x4;

__device__ __forceinline__ short f2bs(float x) {
    union { float f; unsigned u; } v; v.f = x;
    unsigned rr = (v.u + 0x7fffu + ((v.u >> 16) & 1u)) >> 16;  // RNE
    return (short)(rr & 0xffffu);
}

__device__ __forceinline__ float bs2f_lo(int p) {   // low bf16 of packed pair
    union { unsigned u; float f; } v; v.u = (unsigned)p << 16; return v.f;
}
__device__ __forceinline__ float bs2f_hi(int p) {   // high bf16 of packed pair
    union { unsigned u; float f; } v; v.u = (unsigned)p & 0xffff0000u; return v.f;
}

// ---------------- feat -> bf16 ----------------
__global__ __launch_bounds__(256)
void feat2bf16(const float* __restrict__ feat, short* __restrict__ featb) {
    int gid = blockIdx.x * blockDim.x + threadIdx.x;   // 8 elems per thread
    if (gid >= NN * 16) return;
    f32x4 a = ((const f32x4*)feat)[2 * gid];
    f32x4 b = ((const f32x4*)feat)[2 * gid + 1];
    bf16x8 o;
    o[0] = f2bs(a.x); o[1] = f2bs(a.y); o[2] = f2bs(a.z); o[3] = f2bs(a.w);
    o[4] = f2bs(b.x); o[5] = f2bs(b.y); o[6] = f2bs(b.z); o[7] = f2bs(b.w);
    ((bf16x8*)featb)[gid] = o;
}

// ---------------- CSR build: count, 3-phase scan, scatter ----------------
__global__ void count_kernel(const int* __restrict__ dst, int* __restrict__ cnt) {
    int gid = blockIdx.x * blockDim.x + threadIdx.x;
    if (gid >= RE) return;
    int r = gid / EE;
    atomicAdd(&cnt[r * NN + dst[gid]], 1);
}

__global__ __launch_bounds__(256)
void scan_phase1(const int* __restrict__ cnt, int* __restrict__ bsum) {
    __shared__ int sm[4];
    int b = blockIdx.x, t = threadIdx.x;
    int base = b * 1024 + t * 4;
    int s = 0;
    if (base + 3 < RN) {
        int4 v = *(const int4*)(cnt + base);
        s = v.x + v.y + v.z + v.w;
    } else {
        for (int i = 0; i < 4; ++i) if (base + i < RN) s += cnt[base + i];
    }
    #pragma unroll
    for (int m = 1; m < 64; m <<= 1) s += __shfl_xor(s, m);
    if ((t & 63) == 0) sm[t >> 6] = s;
    __syncthreads();
    if (t == 0) bsum[b] = sm[0] + sm[1] + sm[2] + sm[3];
}

__global__ __launch_bounds__(256)
void scan_phase2(int* __restrict__ bsum, int nb) {   // single block
    __shared__ int sm[256];
    int t = threadIdx.x;
    int v = (t < nb) ? bsum[t] : 0;
    sm[t] = v;
    __syncthreads();
    for (int d = 1; d < 256; d <<= 1) {
        int u = (t >= d) ? sm[t - d] : 0;
        __syncthreads();
        sm[t] += u;
        __syncthreads();
    }
    if (t < nb) bsum[t] = sm[t] - v;   // exclusive
}

__global__ __launch_bounds__(256)
void scan_phase3(const int* __restrict__ cnt, const int* __restrict__ bsum,
                 int* __restrict__ off) {
    __shared__ int sm[256];
    int b = blockIdx.x, t = threadIdx.x;
    int base = b * 1024 + t * 4;
    int c0 = 0, c1 = 0, c2 = 0, c3 = 0;
    if (base + 3 < RN) {
        int4 v = *(const int4*)(cnt + base);
        c0 = v.x; c1 = v.y; c2 = v.z; c3 = v.w;
    } else {
        if (base + 0 < RN) c0 = cnt[base + 0];
        if (base + 1 < RN) c1 = cnt[base + 1];
        if (base + 2 < RN) c2 = cnt[base + 2];
        if (base + 3 < RN) c3 = cnt[base + 3];
    }
    int s = c0 + c1 + c2 + c3;
    sm[t] = s;
    __syncthreads();
    for (int d = 1; d < 256; d <<= 1) {
        int u = (t >= d) ? sm[t - d] : 0;
        __syncthreads();
        sm[t] += u;
        __syncthreads();
    }
    int pre = bsum[b] + sm[t] - s;   // exclusive within chunk + chunk base
    if (base + 0 < RN) off[base + 0] = pre;
    if (base + 1 < RN) off[base + 1] = pre + c0;
    if (base + 2 < RN) off[base + 2] = pre + c0 + c1;
    if (base + 3 < RN) off[base + 3] = pre + c0 + c1 + c2;
}

__global__ void scatter_kernel(const int* __restrict__ src, const int* __restrict__ dst,
                               int* __restrict__ off, int* __restrict__ csr) {
    int gid = blockIdx.x * blockDim.x + threadIdx.x;
    if (gid >= RE) return;
    int r = gid / EE;
    int pos = atomicAdd(&off[r * NN + dst[gid]], 1);  // off becomes end-offset
    csr[pos] = src[gid];
}

// ------- aggregation: wave per (r,node), bf16 gather, fused residual add -------
__global__ __launch_bounds__(256)
void gather_kernel(const short* __restrict__ featb,
                   const int* __restrict__ csr,
                   const int* __restrict__ off,   // end offsets (post-scatter)
                   const int* __restrict__ cnt,
                   short* __restrict__ ssumb) {   // [R][N][F] <- bf16(feat + mean)
    int gid = blockIdx.x * blockDim.x + threadIdx.x;
    int w = gid >> 6, lane = gid & 63;
    if (w >= RN) return;
    int c = cnt[w];
    int end = off[w];
    int start = end - c;
    const int* f2 = (const int*)featb;           // 2 bf16 per int
    float ax = 0.0f, ay = 0.0f;
    for (int j = start; j < end; ++j) {
        int s = csr[j];
        int v = f2[(size_t)s * 64 + lane];
        ax += bs2f_lo(v);
        ay += bs2f_hi(v);
    }
    float inv = 1.0f / fmaxf((float)c, 1.0f);
    int n = w % NN;
    int fv = f2[(size_t)n * 64 + lane];
    float hx = bs2f_lo(fv) + ax * inv;
    float hy = bs2f_hi(fv) + ay * inv;
    unsigned plo = (unsigned short)f2bs(hx);
    unsigned phi = (unsigned short)f2bs(hy);
    ((int*)ssumb)[(size_t)w * 64 + lane] = (int)((phi << 16) | plo);
}

// ---------------- fused MFMA transform (2x Linear+LN+relu, final LN, attn scores) ----
#define TW 8

__device__ __forceinline__ void mfma_layer(const bf16x8 A[2][4], const short* Wlds,
                                           int g8, int c, f32x4 acc[2][8]) {
    #pragma unroll
    for (int kk = 0; kk < 4; ++kk) {
        #pragma unroll
        for (int t = 0; t < 8; ++t) {
            int d = t * 16 + c;
            bf16x8 B = *(const bf16x8*)&Wlds[d * 128 + ((kk * 32 + g8) ^ ((d & 7) << 3))];
            acc[0][t] = __builtin_amdgcn_mfma_f32_16x16x32_bf16(A[0][kk], B, acc[0][t], 0, 0, 0);
            acc[1][t] = __builtin_amdgcn_mfma_f32_16x16x32_bf16(A[1][kk], B, acc[1][t], 0, 0, 0);
        }
    }
}

template <bool RELU, bool BIAS>
__device__ __forceinline__ void ln_block(f32x4 acc[2][8], const float* bias,
                                         const float* gam, const float* bet, int c) {
    #pragma unroll
    for (int sub = 0; sub < 2; ++sub) {
        float s0 = 0, s1 = 0, s2 = 0, s3 = 0, p0 = 0, p1 = 0, p2 = 0, p3 = 0;
        #pragma unroll
        for (int t = 0; t < 8; ++t) {
            if (BIAS) {
                float bb = bias[t * 16 + c];
                acc[sub][t][0] += bb; acc[sub][t][1] += bb;
                acc[sub][t][2] += bb; acc[sub][t][3] += bb;
            }
            s0 += acc[sub][t][0]; p0 += acc[sub][t][0] * acc[sub][t][0];
            s1 += acc[sub][t][1]; p1 += acc[sub][t][1] * acc[sub][t][1];
            s2 += acc[sub][t][2]; p2 += acc[sub][t][2] * acc[sub][t][2];
            s3 += acc[sub][t][3]; p3 += acc[sub][t][3] * acc[sub][t][3];
        }
        #pragma unroll
        for (int m = 1; m < 16; m <<= 1) {
            s0 += __shfl_xor(s0, m); s1 += __shfl_xor(s1, m);
            s2 += __shfl_xor(s2, m); s3 += __shfl_xor(s3, m);
            p0 += __shfl_xor(p0, m); p1 += __shfl_xor(p1, m);
            p2 += __shfl_xor(p2, m); p3 += __shfl_xor(p3, m);
        }
        const float inv = 1.0f / 128.0f;
        float mu0 = s0 * inv, mu1 = s1 * inv, mu2 = s2 * inv, mu3 = s3 * inv;
        float r0 = rsqrtf(p0 * inv - mu0 * mu0 + EPSF);
        float r1 = rsqrtf(p1 * inv - mu1 * mu1 + EPSF);
        float r2 = rsqrtf(p2 * inv - mu2 * mu2 + EPSF);
        float r3 = rsqrtf(p3 * inv - mu3 * mu3 + EPSF);
        #pragma unroll
        for (int t = 0; t < 8; ++t) {
            float gg = gam[t * 16 + c], bb = bet[t * 16 + c];
            float v0 = (acc[sub][t][0] - mu0) * r0 * gg + bb;
            float v1 = (acc[sub][t][1] - mu1) * r1 * gg + bb;
            float v2 = (acc[sub][t][2] - mu2) * r2 * gg + bb;
            float v3 = (acc[sub][t][3] - mu3) * r3 * gg + bb;
            if (RELU) {
                v0 = fmaxf(v0, 0.f); v1 = fmaxf(v1, 0.f);
                v2 = fmaxf(v2, 0.f); v3 = fmaxf(v3, 0.f);
            }
            acc[sub][t][0] = v0; acc[sub][t][1] = v1;
            acc[sub][t][2] = v2; acc[sub][t][3] = v3;
        }
    }
}

__device__ __forceinline__ void store_ht(const f32x4 acc[2][8], short* myht, int g, int c) {
    #pragma unroll
    for (int sub = 0; sub < 2; ++sub)
        #pragma unroll
        for (int t = 0; t < 8; ++t) {
            int col = t * 16 + c;
            #pragma unroll
            for (int qq = 0; qq < 4; ++qq) {
                int row = sub * 16 + g * 4 + qq;
                myht[row * 128 + (col ^ ((row & 7) << 3))] = f2bs(acc[sub][t][qq]);
            }
        }
}

__device__ __forceinline__ void load_A(bf16x8 A[2][4], const short* myht, int g8, int c) {
    #pragma unroll
    for (int sub = 0; sub < 2; ++sub)
        #pragma unroll
        for (int kk = 0; kk < 4; ++kk) {
            int row = sub * 16 + c;
            A[sub][kk] = *(const bf16x8*)&myht[row * 128 + ((kk * 32 + g8) ^ ((row & 7) << 3))];
        }
}

__global__ __launch_bounds__(512)
void fused_transform(short* hbuf,                 // ssumb in, h (bf16) out, in-place
                     const float* __restrict__ W0, const float* __restrict__ b0,
                     const float* __restrict__ W1, const float* __restrict__ b1,
                     const float* __restrict__ ln_g, const float* __restrict__ ln_b,
                     const float* __restrict__ LN_g, const float* __restrict__ LN_b,
                     const float* __restrict__ Wa1, const float* __restrict__ Wa2,
                     float* __restrict__ evec) {
    __shared__ short W0t[FF * DD];        // 32 KiB, [d][k] bf16, XOR-swizzled
    __shared__ short W1t[DD * DD];        // 32 KiB
    __shared__ short Wa1t[AA * DD];       // 16 KiB, [a][k]
    __shared__ short ht[TW][32 * DD];     // 64 KiB per-wave h-tiles
    __shared__ float b0s[DD], b1s[DD], lgs[DD], lbs[DD], Lgs[DD], Lbs[DD], wa2s[AA];

    const int r = blockIdx.y;
    const int tid = threadIdx.x;

    for (int i = tid; i < FF * DD; i += 512) {
        int k = i >> 7, d = i & 127;                 // global read coalesced over d
        int idx = d * 128 + (k ^ ((d & 7) << 3));
        W0t[idx] = f2bs(W0[(size_t)r * FF * DD + i]);
        W1t[idx] = f2bs(W1[(size_t)r * DD * DD + i]);
    }
    for (int i = tid; i < DD * AA; i += 512) {
        int k = i >> 6, a = i & 63;
        Wa1t[a * 128 + (k ^ ((a & 7) << 3))] = f2bs(Wa1[(size_t)r * DD * AA + i]);
    }
    if (tid < DD) {
        b0s[tid] = b0[r * DD + tid];
        b1s[tid] = b1[r * DD + tid];
        lgs[tid] = ln_g[r * DD + tid];
        lbs[tid] = ln_b[r * DD + tid];
        Lgs[tid] = LN_g[tid];
        Lbs[tid] = LN_b[tid];
    }
    if (tid < AA) wa2s[tid] = Wa2[r * AA + tid];
    __syncthreads();   // only barrier; per-wave private work below

    const int wv = tid >> 6, ln = tid & 63;
    const int g = ln >> 4, c = ln & 15;
    const int g8 = g * 8;
    short* myht = ht[wv];

    const int ntiles = (NN + 31) / 32;
    for (int tile = blockIdx.x * TW + wv; tile < ntiles; tile += gridDim.x * TW) {
        const int nbase = tile * 32;

        // layer-1 A fragments: bf16 h = feat + neighbor-mean, straight from global
        bf16x8 A1[2][4];
        #pragma unroll
        for (int sub = 0; sub < 2; ++sub) {
            int n = nbase + sub * 16 + c;
            if (n > NN - 1) n = NN - 1;              // duplicate row; stores guarded
            const short* sp = hbuf + ((size_t)r * NN + n) * FF;
            #pragma unroll
            for (int kk = 0; kk < 4; ++kk)
                A1[sub][kk] = *(const bf16x8*)(sp + kk * 32 + g8);
        }

        f32x4 acc[2][8];
        #pragma unroll
        for (int sub = 0; sub < 2; ++sub)
            #pragma unroll
            for (int t = 0; t < 8; ++t) acc[sub][t] = (f32x4){0.f, 0.f, 0.f, 0.f};

        // layer 1
        mfma_layer(A1, W0t, g8, c, acc);
        ln_block<true, true>(acc, b0s, lgs, lbs, c);
        store_ht(acc, myht, g, c);

        // layer 2
        bf16x8 A2[2][4];
        load_A(A2, myht, g8, c);
        #pragma unroll
        for (int sub = 0; sub < 2; ++sub)
            #pragma unroll
            for (int t = 0; t < 8; ++t) acc[sub][t] = (f32x4){0.f, 0.f, 0.f, 0.f};
        mfma_layer(A2, W1t, g8, c, acc);
        ln_block<true, true>(acc, b1s, lgs, lbs, c);
        // final LayerNorm (no relu, shared gamma/beta)
        ln_block<false, false>(acc, nullptr, Lgs, Lbs, c);
        store_ht(acc, myht, g, c);

        // copy h tile LDS -> global, coalesced 1KB/instr (global tile is contiguous)
        {
            short* gout = hbuf + ((size_t)r * NN + nbase) * FF;
            const int rows_valid = (nbase + 32 <= NN) ? 32 : (NN - nbase);
            #pragma unroll
            for (int cc = 0; cc < 8; ++cc) {
                int row = cc * 4 + (ln >> 4);
                int col0 = (ln & 15) * 8;
                bf16x8 v = *(const bf16x8*)&myht[row * 128 + (col0 ^ ((row & 7) << 3))];
                if (row < rows_valid) *(bf16x8*)&gout[row * FF + col0] = v;
            }
        }

        // semantic attention scores: e = tanh(h @ Wa1) . Wa2
        bf16x8 A3[2][4];
        load_A(A3, myht, g8, c);
        f32x4 accA[2][4];
        #pragma unroll
        for (int sub = 0; sub < 2; ++sub)
            #pragma unroll
            for (int t = 0; t < 4; ++t) accA[sub][t] = (f32x4){0.f, 0.f, 0.f, 0.f};
        #pragma unroll
        for (int kk = 0; kk < 4; ++kk)
            #pragma unroll
            for (int t = 0; t < 4; ++t) {
                int a_ = t * 16 + c;
                bf16x8 B = *(const bf16x8*)&Wa1t[a_ * 128 + ((kk * 32 + g8) ^ ((a_ & 7) << 3))];
                accA[0][t] = __builtin_amdgcn_mfma_f32_16x16x32_bf16(A3[0][kk], B, accA[0][t], 0, 0, 0);
                accA[1][t] = __builtin_amdgcn_mfma_f32_16x16x32_bf16(A3[1][kk], B, accA[1][t], 0, 0, 0);
            }
        #pragma unroll
        for (int sub = 0; sub < 2; ++sub) {
            float e0 = 0, e1 = 0, e2 = 0, e3 = 0;
            #pragma unroll
            for (int t = 0; t < 4; ++t) {
                float w2v = wa2s[t * 16 + c];
                e0 += tanhf(accA[sub][t][0]) * w2v;
                e1 += tanhf(accA[sub][t][1]) * w2v;
                e2 += tanhf(accA[sub][t][2]) * w2v;
                e3 += tanhf(accA[sub][t][3]) * w2v;
            }
            #pragma unroll
            for (int m = 1; m < 16; m <<= 1) {
                e0 += __shfl_xor(e0, m); e1 += __shfl_xor(e1, m);
                e2 += __shfl_xor(e2, m); e3 += __shfl_xor(e3, m);
            }
            int nb = nbase + sub * 16 + g * 4;
            if (c == 0 && nb + 0 < NN) evec[(size_t)r * NN + nb + 0] = e0;
            if (c == 1 && nb + 1 < NN) evec[(size_t)r * NN + nb + 1] = e1;
            if (c == 2 && nb + 2 < NN) evec[(size_t)r * NN + nb + 2] = e2;
            if (c == 3 && nb + 3 < NN) evec[(size_t)r * NN + nb + 3] = e3;
        }
    }
}

// ---------------- softmax over relations + weighted combine ----------------
__global__ __launch_bounds__(256)
void combine_kernel(const short* __restrict__ hfb,    // [R][N][D] bf16
                    const float* __restrict__ evec,   // [R][N]
                    float* __restrict__ out) {        // [N][D] fp32
    int gid = blockIdx.x * blockDim.x + threadIdx.x;
    if (gid >= NN * 64) return;
    int n = gid >> 6, j = gid & 63;
    float e0 = evec[n], e1 = evec[NN + n], e2 = evec[2 * NN + n];
    float m = fmaxf(e0, fmaxf(e1, e2));
    float w0 = __expf(e0 - m), w1 = __expf(e1 - m), w2 = __expf(e2 - m);
    float inv = 1.0f / (w0 + w1 + w2);
    w0 *= inv; w1 *= inv; w2 *= inv;
    const int* h0 = (const int*)hfb + (size_t)n * 64;
    const int* h1 = (const int*)hfb + ((size_t)NN + n) * 64;
    const int* h2 = (const int*)hfb + ((size_t)2 * NN + n) * 64;
    int a = h0[j], b = h1[j], d = h2[j];
    float2 o;
    o.x = w0 * bs2f_lo(a) + w1 * bs2f_lo(b) + w2 * bs2f_lo(d);
    o.y = w0 * bs2f_hi(a) + w1 * bs2f_hi(b) + w2 * bs2f_hi(d);
    ((float2*)out)[(size_t)n * 64 + j] = o;
}

extern "C" void kernel_launch(void* const* d_in, const int* in_sizes, int n_in,
                              void* d_out, int out_size, void* d_ws, size_t ws_size,
                              hipStream_t stream) {
    const float* feat = (const float*)d_in[0];
    const int*   src  = (const int*)d_in[1];
    const int*   dst  = (const int*)d_in[2];
    const float* W0   = (const float*)d_in[3];
    const float* b0   = (const float*)d_in[4];
    const float* W1   = (const float*)d_in[5];
    const float* b1   = (const float*)d_in[6];
    const float* ln_g = (const float*)d_in[7];
    const float* ln_b = (const float*)d_in[8];
    const float* LN_g = (const float*)d_in[9];
    const float* LN_b = (const float*)d_in[10];
    const float* Wa1  = (const float*)d_in[11];
    const float* Wa2  = (const float*)d_in[12];
    float* out = (float*)d_out;

    // workspace layout
    short* ssumb = (short*)d_ws;                        // RN*FF bf16 (38.4 MB), in-place h
    short* featb = ssumb + (size_t)RN * FF;             // NN*FF bf16 (12.8 MB)
    int*   cnt   = (int*)(featb + (size_t)NN * FF);     // RN
    int*   off   = cnt + RN;                            // RN
    int*   csr   = off + RN;                            // RE
    float* evec  = (float*)(csr + RE);                  // RN
    int*   bsum  = (int*)(evec + RN);                   // 147

    const int NB = (RN + 1023) / 1024;                  // 147

    feat2bf16<<<(NN * 16 + 255) / 256, 256, 0, stream>>>(feat, featb);
    hipMemsetAsync(cnt, 0, (size_t)RN * sizeof(int), stream);
    count_kernel<<<(RE + 255) / 256, 256, 0, stream>>>(dst, cnt);
    scan_phase1<<<NB, 256, 0, stream>>>(cnt, bsum);
    scan_phase2<<<1, 256, 0, stream>>>(bsum, NB);
    scan_phase3<<<NB, 256, 0, stream>>>(cnt, bsum, off);
    scatter_kernel<<<(RE + 255) / 256, 256, 0, stream>>>(src, dst, off, csr);
    gather_kernel<<<(RN * 64 + 255) / 256, 256, 0, stream>>>(featb, csr, off, cnt, ssumb);

    const int ntiles = (NN + 31) / 32;                  // 1563
    fused_transform<<<dim3((ntiles + TW - 1) / TW, RR), 512, 0, stream>>>(
        ssumb, W0, b0, W1, b1, ln_g, ln_b, LN_g, LN_b, Wa1, Wa2, evec);
    combine_kernel<<<(NN * 64 + 255) / 256, 256, 0, stream>>>(ssumb, evec, out);
}

// Round 5
// 494.700 us; speedup vs baseline: 3.6884x; 1.2526x over previous
//
#include <hip/hip_runtime.h>

#define RR 3
#define NN 50000
#define EE 800000
#define FF 128
#define DD 128
#define AA 64
#define EPSF 1e-5f
#define RN (RR * NN)
#define RE (RR * EE)

typedef __attribute__((ext_vector_type(8))) short bf16x8;
typedef __attribute__((ext_vector_type(4))) float f32x4;

__device__ __forceinline__ short f2bs(float x) {
    union { float f; unsigned u; } v; v.f = x;
    unsigned rr = (v.u + 0x7fffu + ((v.u >> 16) & 1u)) >> 16;  // RNE
    return (short)(rr & 0xffffu);
}

__device__ __forceinline__ float bs2f_lo(int p) {   // low bf16 of packed pair
    union { unsigned u; float f; } v; v.u = (unsigned)p << 16; return v.f;
}
__device__ __forceinline__ float bs2f_hi(int p) {   // high bf16 of packed pair
    union { unsigned u; float f; } v; v.u = (unsigned)p & 0xffff0000u; return v.f;
}

// ---------------- feat -> bf16 ----------------
__global__ __launch_bounds__(256)
void feat2bf16(const float* __restrict__ feat, short* __restrict__ featb) {
    int gid = blockIdx.x * blockDim.x + threadIdx.x;   // 8 elems per thread
    if (gid >= NN * 16) return;
    f32x4 a = ((const f32x4*)feat)[2 * gid];
    f32x4 b = ((const f32x4*)feat)[2 * gid + 1];
    bf16x8 o;
    o[0] = f2bs(a.x); o[1] = f2bs(a.y); o[2] = f2bs(a.z); o[3] = f2bs(a.w);
    o[4] = f2bs(b.x); o[5] = f2bs(b.y); o[6] = f2bs(b.z); o[7] = f2bs(b.w);
    ((bf16x8*)featb)[gid] = o;
}

// ---------------- CSR build: count, 3-phase scan, scatter ----------------
__global__ void count_kernel(const int* __restrict__ dst, int* __restrict__ cnt) {
    int gid = blockIdx.x * blockDim.x + threadIdx.x;
    if (gid >= RE) return;
    int r = gid / EE;
    atomicAdd(&cnt[r * NN + dst[gid]], 1);
}

__global__ __launch_bounds__(256)
void scan_phase1(const int* __restrict__ cnt, int* __restrict__ bsum) {
    __shared__ int sm[4];
    int b = blockIdx.x, t = threadIdx.x;
    int base = b * 1024 + t * 4;
    int s = 0;
    if (base + 3 < RN) {
        int4 v = *(const int4*)(cnt + base);
        s = v.x + v.y + v.z + v.w;
    } else {
        for (int i = 0; i < 4; ++i) if (base + i < RN) s += cnt[base + i];
    }
    #pragma unroll
    for (int m = 1; m < 64; m <<= 1) s += __shfl_xor(s, m);
    if ((t & 63) == 0) sm[t >> 6] = s;
    __syncthreads();
    if (t == 0) bsum[b] = sm[0] + sm[1] + sm[2] + sm[3];
}

__global__ __launch_bounds__(256)
void scan_phase2(int* __restrict__ bsum, int nb) {   // single block
    __shared__ int sm[256];
    int t = threadIdx.x;
    int v = (t < nb) ? bsum[t] : 0;
    sm[t] = v;
    __syncthreads();
    for (int d = 1; d < 256; d <<= 1) {
        int u = (t >= d) ? sm[t - d] : 0;
        __syncthreads();
        sm[t] += u;
        __syncthreads();
    }
    if (t < nb) bsum[t] = sm[t] - v;   // exclusive
}

__global__ __launch_bounds__(256)
void scan_phase3(const int* __restrict__ cnt, const int* __restrict__ bsum,
                 int* __restrict__ off) {
    __shared__ int sm[256];
    int b = blockIdx.x, t = threadIdx.x;
    int base = b * 1024 + t * 4;
    int c0 = 0, c1 = 0, c2 = 0, c3 = 0;
    if (base + 3 < RN) {
        int4 v = *(const int4*)(cnt + base);
        c0 = v.x; c1 = v.y; c2 = v.z; c3 = v.w;
    } else {
        if (base + 0 < RN) c0 = cnt[base + 0];
        if (base + 1 < RN) c1 = cnt[base + 1];
        if (base + 2 < RN) c2 = cnt[base + 2];
        if (base + 3 < RN) c3 = cnt[base + 3];
    }
    int s = c0 + c1 + c2 + c3;
    sm[t] = s;
    __syncthreads();
    for (int d = 1; d < 256; d <<= 1) {
        int u = (t >= d) ? sm[t - d] : 0;
        __syncthreads();
        sm[t] += u;
        __syncthreads();
    }
    int pre = bsum[b] + sm[t] - s;   // exclusive within chunk + chunk base
    if (base + 0 < RN) off[base + 0] = pre;
    if (base + 1 < RN) off[base + 1] = pre + c0;
    if (base + 2 < RN) off[base + 2] = pre + c0 + c1;
    if (base + 3 < RN) off[base + 3] = pre + c0 + c1 + c2;
}

__global__ void scatter_kernel(const int* __restrict__ src, const int* __restrict__ dst,
                               int* __restrict__ off, int* __restrict__ csr) {
    int gid = blockIdx.x * blockDim.x + threadIdx.x;
    if (gid >= RE) return;
    int r = gid / EE;
    int pos = atomicAdd(&off[r * NN + dst[gid]], 1);  // off becomes end-offset
    csr[pos] = src[gid];
}

// ------- aggregation: wave per (r,node), 4-way MLP-unrolled bf16 gather -------
__global__ __launch_bounds__(256)
void gather_kernel(const short* __restrict__ featb,
                   const int* __restrict__ csr,
                   const int* __restrict__ off,   // end offsets (post-scatter)
                   const int* __restrict__ cnt,
                   short* __restrict__ ssumb) {   // [R][N][F] <- bf16(feat + mean)
    int gid = blockIdx.x * blockDim.x + threadIdx.x;
    int w = gid >> 6, lane = gid & 63;
    if (w >= RN) return;
    int c = cnt[w];
    int end = off[w];
    int start = end - c;
    const int* f2 = (const int*)featb;           // 2 bf16 per int
    float ax0 = 0.f, ay0 = 0.f, ax1 = 0.f, ay1 = 0.f;
    float ax2 = 0.f, ay2 = 0.f, ax3 = 0.f, ay3 = 0.f;
    int j = start;
    // 4 independent row-load chains in flight
    for (; j + 3 < end; j += 4) {
        int s0 = csr[j + 0];
        int s1 = csr[j + 1];
        int s2 = csr[j + 2];
        int s3 = csr[j + 3];
        int v0 = f2[(size_t)s0 * 64 + lane];
        int v1 = f2[(size_t)s1 * 64 + lane];
        int v2 = f2[(size_t)s2 * 64 + lane];
        int v3 = f2[(size_t)s3 * 64 + lane];
        ax0 += bs2f_lo(v0); ay0 += bs2f_hi(v0);
        ax1 += bs2f_lo(v1); ay1 += bs2f_hi(v1);
        ax2 += bs2f_lo(v2); ay2 += bs2f_hi(v2);
        ax3 += bs2f_lo(v3); ay3 += bs2f_hi(v3);
    }
    for (; j < end; ++j) {
        int s = csr[j];
        int v = f2[(size_t)s * 64 + lane];
        ax0 += bs2f_lo(v); ay0 += bs2f_hi(v);
    }
    float ax = (ax0 + ax1) + (ax2 + ax3);
    float ay = (ay0 + ay1) + (ay2 + ay3);
    float inv = 1.0f / fmaxf((float)c, 1.0f);
    int n = w % NN;
    int fv = f2[(size_t)n * 64 + lane];
    float hx = bs2f_lo(fv) + ax * inv;
    float hy = bs2f_hi(fv) + ay * inv;
    unsigned plo = (unsigned short)f2bs(hx);
    unsigned phi = (unsigned short)f2bs(hy);
    ((int*)ssumb)[(size_t)w * 64 + lane] = (int)((phi << 16) | plo);
}

// ---------------- fused MFMA transform (2x Linear+LN+relu, final LN, attn scores) ----
#define TW 8

__device__ __forceinline__ void mfma_layer(const bf16x8 A[2][4], const short* Wlds,
                                           int g8, int c, f32x4 acc[2][8]) {
    #pragma unroll
    for (int kk = 0; kk < 4; ++kk) {
        #pragma unroll
        for (int t = 0; t < 8; ++t) {
            int d = t * 16 + c;
            bf16x8 B = *(const bf16x8*)&Wlds[d * 128 + ((kk * 32 + g8) ^ ((d & 7) << 3))];
            acc[0][t] = __builtin_amdgcn_mfma_f32_16x16x32_bf16(A[0][kk], B, acc[0][t], 0, 0, 0);
            acc[1][t] = __builtin_amdgcn_mfma_f32_16x16x32_bf16(A[1][kk], B, acc[1][t], 0, 0, 0);
        }
    }
}

template <bool RELU, bool BIAS>
__device__ __forceinline__ void ln_block(f32x4 acc[2][8], const float* bias,
                                         const float* gam, const float* bet, int c) {
    #pragma unroll
    for (int sub = 0; sub < 2; ++sub) {
        float s0 = 0, s1 = 0, s2 = 0, s3 = 0, p0 = 0, p1 = 0, p2 = 0, p3 = 0;
        #pragma unroll
        for (int t = 0; t < 8; ++t) {
            if (BIAS) {
                float bb = bias[t * 16 + c];
                acc[sub][t][0] += bb; acc[sub][t][1] += bb;
                acc[sub][t][2] += bb; acc[sub][t][3] += bb;
            }
            s0 += acc[sub][t][0]; p0 += acc[sub][t][0] * acc[sub][t][0];
            s1 += acc[sub][t][1]; p1 += acc[sub][t][1] * acc[sub][t][1];
            s2 += acc[sub][t][2]; p2 += acc[sub][t][2] * acc[sub][t][2];
            s3 += acc[sub][t][3]; p3 += acc[sub][t][3] * acc[sub][t][3];
        }
        #pragma unroll
        for (int m = 1; m < 16; m <<= 1) {
            s0 += __shfl_xor(s0, m); s1 += __shfl_xor(s1, m);
            s2 += __shfl_xor(s2, m); s3 += __shfl_xor(s3, m);
            p0 += __shfl_xor(p0, m); p1 += __shfl_xor(p1, m);
            p2 += __shfl_xor(p2, m); p3 += __shfl_xor(p3, m);
        }
        const float inv = 1.0f / 128.0f;
        float mu0 = s0 * inv, mu1 = s1 * inv, mu2 = s2 * inv, mu3 = s3 * inv;
        float r0 = rsqrtf(p0 * inv - mu0 * mu0 + EPSF);
        float r1 = rsqrtf(p1 * inv - mu1 * mu1 + EPSF);
        float r2 = rsqrtf(p2 * inv - mu2 * mu2 + EPSF);
        float r3 = rsqrtf(p3 * inv - mu3 * mu3 + EPSF);
        #pragma unroll
        for (int t = 0; t < 8; ++t) {
            float gg = gam[t * 16 + c], bb = bet[t * 16 + c];
            float v0 = (acc[sub][t][0] - mu0) * r0 * gg + bb;
            float v1 = (acc[sub][t][1] - mu1) * r1 * gg + bb;
            float v2 = (acc[sub][t][2] - mu2) * r2 * gg + bb;
            float v3 = (acc[sub][t][3] - mu3) * r3 * gg + bb;
            if (RELU) {
                v0 = fmaxf(v0, 0.f); v1 = fmaxf(v1, 0.f);
                v2 = fmaxf(v2, 0.f); v3 = fmaxf(v3, 0.f);
            }
            acc[sub][t][0] = v0; acc[sub][t][1] = v1;
            acc[sub][t][2] = v2; acc[sub][t][3] = v3;
        }
    }
}

__device__ __forceinline__ void store_ht(const f32x4 acc[2][8], short* myht, int g, int c) {
    #pragma unroll
    for (int sub = 0; sub < 2; ++sub)
        #pragma unroll
        for (int t = 0; t < 8; ++t) {
            int col = t * 16 + c;
            #pragma unroll
            for (int qq = 0; qq < 4; ++qq) {
                int row = sub * 16 + g * 4 + qq;
                myht[row * 128 + (col ^ ((row & 7) << 3))] = f2bs(acc[sub][t][qq]);
            }
        }
}

__device__ __forceinline__ void load_A(bf16x8 A[2][4], const short* myht, int g8, int c) {
    #pragma unroll
    for (int sub = 0; sub < 2; ++sub)
        #pragma unroll
        for (int kk = 0; kk < 4; ++kk) {
            int row = sub * 16 + c;
            A[sub][kk] = *(const bf16x8*)&myht[row * 128 + ((kk * 32 + g8) ^ ((row & 7) << 3))];
        }
}

__global__ __launch_bounds__(512)
void fused_transform(short* hbuf,                 // ssumb in, h (bf16) out, in-place
                     const float* __restrict__ W0, const float* __restrict__ b0,
                     const float* __restrict__ W1, const float* __restrict__ b1,
                     const float* __restrict__ ln_g, const float* __restrict__ ln_b,
                     const float* __restrict__ LN_g, const float* __restrict__ LN_b,
                     const float* __restrict__ Wa1, const float* __restrict__ Wa2,
                     float* __restrict__ evec) {
    __shared__ short W0t[FF * DD];        // 32 KiB, [d][k] bf16, XOR-swizzled
    __shared__ short W1t[DD * DD];        // 32 KiB
    __shared__ short Wa1t[AA * DD];       // 16 KiB, [a][k]
    __shared__ short ht[TW][32 * DD];     // 64 KiB per-wave h-tiles
    __shared__ float b0s[DD], b1s[DD], lgs[DD], lbs[DD], Lgs[DD], Lbs[DD], wa2s[AA];

    const int r = blockIdx.y;
    const int tid = threadIdx.x;

    for (int i = tid; i < FF * DD; i += 512) {
        int k = i >> 7, d = i & 127;                 // global read coalesced over d
        int idx = d * 128 + (k ^ ((d & 7) << 3));
        W0t[idx] = f2bs(W0[(size_t)r * FF * DD + i]);
        W1t[idx] = f2bs(W1[(size_t)r * DD * DD + i]);
    }
    for (int i = tid; i < DD * AA; i += 512) {
        int k = i >> 6, a = i & 63;
        Wa1t[a * 128 + (k ^ ((a & 7) << 3))] = f2bs(Wa1[(size_t)r * DD * AA + i]);
    }
    if (tid < DD) {
        b0s[tid] = b0[r * DD + tid];
        b1s[tid] = b1[r * DD + tid];
        lgs[tid] = ln_g[r * DD + tid];
        lbs[tid] = ln_b[r * DD + tid];
        Lgs[tid] = LN_g[tid];
        Lbs[tid] = LN_b[tid];
    }
    if (tid < AA) wa2s[tid] = Wa2[r * AA + tid];
    __syncthreads();   // only barrier; per-wave private work below

    const int wv = tid >> 6, ln = tid & 63;
    const int g = ln >> 4, c = ln & 15;
    const int g8 = g * 8;
    short* myht = ht[wv];

    const int ntiles = (NN + 31) / 32;
    for (int tile = blockIdx.x * TW + wv; tile < ntiles; tile += gridDim.x * TW) {
        const int nbase = tile * 32;

        // layer-1 A fragments: bf16 h = feat + neighbor-mean, straight from global
        bf16x8 A1[2][4];
        #pragma unroll
        for (int sub = 0; sub < 2; ++sub) {
            int n = nbase + sub * 16 + c;
            if (n > NN - 1) n = NN - 1;              // duplicate row; stores guarded
            const short* sp = hbuf + ((size_t)r * NN + n) * FF;
            #pragma unroll
            for (int kk = 0; kk < 4; ++kk)
                A1[sub][kk] = *(const bf16x8*)(sp + kk * 32 + g8);
        }

        f32x4 acc[2][8];
        #pragma unroll
        for (int sub = 0; sub < 2; ++sub)
            #pragma unroll
            for (int t = 0; t < 8; ++t) acc[sub][t] = (f32x4){0.f, 0.f, 0.f, 0.f};

        // layer 1
        mfma_layer(A1, W0t, g8, c, acc);
        ln_block<true, true>(acc, b0s, lgs, lbs, c);
        store_ht(acc, myht, g, c);

        // layer 2
        bf16x8 A2[2][4];
        load_A(A2, myht, g8, c);
        #pragma unroll
        for (int sub = 0; sub < 2; ++sub)
            #pragma unroll
            for (int t = 0; t < 8; ++t) acc[sub][t] = (f32x4){0.f, 0.f, 0.f, 0.f};
        mfma_layer(A2, W1t, g8, c, acc);
        ln_block<true, true>(acc, b1s, lgs, lbs, c);
        // final LayerNorm (no relu, shared gamma/beta)
        ln_block<false, false>(acc, nullptr, Lgs, Lbs, c);
        store_ht(acc, myht, g, c);

        // copy h tile LDS -> global, coalesced 1KB/instr (global tile is contiguous)
        {
            short* gout = hbuf + ((size_t)r * NN + nbase) * FF;
            const int rows_valid = (nbase + 32 <= NN) ? 32 : (NN - nbase);
            #pragma unroll
            for (int cc = 0; cc < 8; ++cc) {
                int row = cc * 4 + (ln >> 4);
                int col0 = (ln & 15) * 8;
                bf16x8 v = *(const bf16x8*)&myht[row * 128 + (col0 ^ ((row & 7) << 3))];
                if (row < rows_valid) *(bf16x8*)&gout[row * FF + col0] = v;
            }
        }

        // semantic attention scores: e = tanh(h @ Wa1) . Wa2
        bf16x8 A3[2][4];
        load_A(A3, myht, g8, c);
        f32x4 accA[2][4];
        #pragma unroll
        for (int sub = 0; sub < 2; ++sub)
            #pragma unroll
            for (int t = 0; t < 4; ++t) accA[sub][t] = (f32x4){0.f, 0.f, 0.f, 0.f};
        #pragma unroll
        for (int kk = 0; kk < 4; ++kk)
            #pragma unroll
            for (int t = 0; t < 4; ++t) {
                int a_ = t * 16 + c;
                bf16x8 B = *(const bf16x8*)&Wa1t[a_ * 128 + ((kk * 32 + g8) ^ ((a_ & 7) << 3))];
                accA[0][t] = __builtin_amdgcn_mfma_f32_16x16x32_bf16(A3[0][kk], B, accA[0][t], 0, 0, 0);
                accA[1][t] = __builtin_amdgcn_mfma_f32_16x16x32_bf16(A3[1][kk], B, accA[1][t], 0, 0, 0);
            }
        #pragma unroll
        for (int sub = 0; sub < 2; ++sub) {
            float e0 = 0, e1 = 0, e2 = 0, e3 = 0;
            #pragma unroll
            for (int t = 0; t < 4; ++t) {
                float w2v = wa2s[t * 16 + c];
                e0 += tanhf(accA[sub][t][0]) * w2v;
                e1 += tanhf(accA[sub][t][1]) * w2v;
                e2 += tanhf(accA[sub][t][2]) * w2v;
                e3 += tanhf(accA[sub][t][3]) * w2v;
            }
            #pragma unroll
            for (int m = 1; m < 16; m <<= 1) {
                e0 += __shfl_xor(e0, m); e1 += __shfl_xor(e1, m);
                e2 += __shfl_xor(e2, m); e3 += __shfl_xor(e3, m);
            }
            int nb = nbase + sub * 16 + g * 4;
            if (c == 0 && nb + 0 < NN) evec[(size_t)r * NN + nb + 0] = e0;
            if (c == 1 && nb + 1 < NN) evec[(size_t)r * NN + nb + 1] = e1;
            if (c == 2 && nb + 2 < NN) evec[(size_t)r * NN + nb + 2] = e2;
            if (c == 3 && nb + 3 < NN) evec[(size_t)r * NN + nb + 3] = e3;
        }
    }
}

// ---------------- softmax over relations + weighted combine ----------------
__global__ __launch_bounds__(256)
void combine_kernel(const short* __restrict__ hfb,    // [R][N][D] bf16
                    const float* __restrict__ evec,   // [R][N]
                    float* __restrict__ out) {        // [N][D] fp32
    int gid = blockIdx.x * blockDim.x + threadIdx.x;
    if (gid >= NN * 64) return;
    int n = gid >> 6, j = gid & 63;
    float e0 = evec[n], e1 = evec[NN + n], e2 = evec[2 * NN + n];
    float m = fmaxf(e0, fmaxf(e1, e2));
    float w0 = __expf(e0 - m), w1 = __expf(e1 - m), w2 = __expf(e2 - m);
    float inv = 1.0f / (w0 + w1 + w2);
    w0 *= inv; w1 *= inv; w2 *= inv;
    const int* h0 = (const int*)hfb + (size_t)n * 64;
    const int* h1 = (const int*)hfb + ((size_t)NN + n) * 64;
    const int* h2 = (const int*)hfb + ((size_t)2 * NN + n) * 64;
    int a = h0[j], b = h1[j], d = h2[j];
    float2 o;
    o.x = w0 * bs2f_lo(a) + w1 * bs2f_lo(b) + w2 * bs2f_lo(d);
    o.y = w0 * bs2f_hi(a) + w1 * bs2f_hi(b) + w2 * bs2f_hi(d);
    ((float2*)out)[(size_t)n * 64 + j] = o;
}

extern "C" void kernel_launch(void* const* d_in, const int* in_sizes, int n_in,
                              void* d_out, int out_size, void* d_ws, size_t ws_size,
                              hipStream_t stream) {
    const float* feat = (const float*)d_in[0];
    const int*   src  = (const int*)d_in[1];
    const int*   dst  = (const int*)d_in[2];
    const float* W0   = (const float*)d_in[3];
    const float* b0   = (const float*)d_in[4];
    const float* W1   = (const float*)d_in[5];
    const float* b1   = (const float*)d_in[6];
    const float* ln_g = (const float*)d_in[7];
    const float* ln_b = (const float*)d_in[8];
    const float* LN_g = (const float*)d_in[9];
    const float* LN_b = (const float*)d_in[10];
    const float* Wa1  = (const float*)d_in[11];
    const float* Wa2  = (const float*)d_in[12];
    float* out = (float*)d_out;

    // workspace layout
    short* ssumb = (short*)d_ws;                        // RN*FF bf16 (38.4 MB), in-place h
    short* featb = ssumb + (size_t)RN * FF;             // NN*FF bf16 (12.8 MB)
    int*   cnt   = (int*)(featb + (size_t)NN * FF);     // RN
    int*   off   = cnt + RN;                            // RN
    int*   csr   = off + RN;                            // RE
    float* evec  = (float*)(csr + RE);                  // RN
    int*   bsum  = (int*)(evec + RN);                   // 147

    const int NB = (RN + 1023) / 1024;                  // 147

    feat2bf16<<<(NN * 16 + 255) / 256, 256, 0, stream>>>(feat, featb);
    hipMemsetAsync(cnt, 0, (size_t)RN * sizeof(int), stream);
    count_kernel<<<(RE + 255) / 256, 256, 0, stream>>>(dst, cnt);
    scan_phase1<<<NB, 256, 0, stream>>>(cnt, bsum);
    scan_phase2<<<1, 256, 0, stream>>>(bsum, NB);
    scan_phase3<<<NB, 256, 0, stream>>>(cnt, bsum, off);
    scatter_kernel<<<(RE + 255) / 256, 256, 0, stream>>>(src, dst, off, csr);
    gather_kernel<<<(RN * 64 + 255) / 256, 256, 0, stream>>>(featb, csr, off, cnt, ssumb);

    const int ntiles = (NN + 31) / 32;                  // 1563
    fused_transform<<<dim3((ntiles + TW - 1) / TW, RR), 512, 0, stream>>>(
        ssumb, W0, b0, W1, b1, ln_g, ln_b, LN_g, LN_b, Wa1, Wa2, evec);
    combine_kernel<<<(NN * 64 + 255) / 256, 256, 0, stream>>>(ssumb, evec, out);
}